// Round 10
// baseline (655.810 us; speedup 1.0000x reference)
//
#include <hip/hip_runtime.h>
#include <hip/hip_bf16.h>
#include <stdint.h>

// MoE FFN: B=2,T=2048,D=1024,F=4096,E=8,K=2. S=4096 tokens, 8192 assignments.
#define S_TOK 4096
#define DDIM  1024
#define FDIM  4096
#define EEXP  8
#define CAP   (S_TOK * 2)

typedef __bf16 bf16x8 __attribute__((ext_vector_type(8)));
typedef __bf16 bf16x4 __attribute__((ext_vector_type(4)));
typedef float  f32x4  __attribute__((ext_vector_type(4)));

__device__ __forceinline__ unsigned short f2bf(float f) {
    union { float f; unsigned u; } v; v.f = f;
    unsigned u = v.u;
    return (unsigned short)((u + 0x7FFFu + ((u >> 16) & 1u)) >> 16);  // RNE
}

// global -> LDS async copy, 16B/lane. Offset arg MUST stay 0 (r8 lesson).
__device__ __forceinline__ void gload16(const void* g, void* l) {
    auto gp = reinterpret_cast<const __attribute__((address_space(1))) uint32_t*>(
        reinterpret_cast<uintptr_t>(g));
    auto lp = reinterpret_cast<__attribute__((address_space(3))) uint32_t*>(
        static_cast<uint32_t>(reinterpret_cast<uintptr_t>(l)));
    __builtin_amdgcn_global_load_lds(gp, lp, 16, 0, 0);
}

// ---------------- small kernels ----------------

__global__ void zero_k(int* p, int n) {
    int i = threadIdx.x;
    if (i < n) p[i] = 0;
}

__global__ void cvt_bf16(const float* __restrict__ src, unsigned short* __restrict__ dst, int n4) {
    int stride = gridDim.x * blockDim.x;
    for (int i = blockIdx.x * blockDim.x + threadIdx.x; i < n4; i += stride) {
        float4 v = ((const float4*)src)[i];
        bf16x4 o = { (__bf16)v.x, (__bf16)v.y, (__bf16)v.z, (__bf16)v.w };
        ((bf16x4*)dst)[i] = o;
    }
}

// Router: one wave per token, fp32 (must match numpy top-2 selection). Fused x->bf16.
__global__ void router_k(const float* __restrict__ x, const float* __restrict__ gw,
                         unsigned short* __restrict__ xb,
                         int* __restrict__ topk_e, float* __restrict__ topk_g,
                         int* __restrict__ counts) {
    int s = blockIdx.x;
    int l = threadIdx.x;
    const float* xr = x + (size_t)s * DDIM;
    unsigned short* xbr = xb + (size_t)s * DDIM;
    float acc[EEXP];
#pragma unroll
    for (int e = 0; e < EEXP; ++e) acc[e] = 0.f;
    for (int i = 0; i < DDIM; i += 64) {
        float xv = xr[i + l];
        xbr[i + l] = f2bf(xv);
#pragma unroll
        for (int e = 0; e < EEXP; ++e) acc[e] = fmaf(xv, gw[e * DDIM + i + l], acc[e]);
    }
#pragma unroll
    for (int e = 0; e < EEXP; ++e)
        for (int off = 32; off > 0; off >>= 1) acc[e] += __shfl_down(acc[e], off, 64);
    if (l == 0) {
        float v0 = -1e30f, v1 = -1e30f; int i0 = 0, i1 = 0;
#pragma unroll
        for (int e = 0; e < EEXP; ++e) {
            float v = acc[e];
            if (v > v0)      { v1 = v0; i1 = i0; v0 = v; i0 = e; }
            else if (v > v1) { v1 = v;  i1 = e; }
        }
        float t = expf(v1 - v0);
        float d = 1.f + t;
        topk_e[2 * s] = i0; topk_e[2 * s + 1] = i1;
        topk_g[2 * s] = 1.f / d; topk_g[2 * s + 1] = t / d;
        atomicAdd(&counts[i0], 1);
        atomicAdd(&counts[i1], 1);
    }
}

__global__ void scan_k(const int* __restrict__ counts, int* __restrict__ basep) {
    if (threadIdx.x == 0) {
        int b = 0;
        for (int e = 0; e < EEXP; ++e) { basep[e] = b; b += counts[e]; }
    }
}

__global__ void scatter_k(const int* __restrict__ topk_e, int* __restrict__ rankctr,
                          const int* __restrict__ basep, int* __restrict__ arena_token,
                          int* __restrict__ pos_of) {
    int s = blockIdx.x * blockDim.x + threadIdx.x;
    if (s >= S_TOK) return;
#pragma unroll
    for (int t = 0; t < 2; ++t) {
        int e = topk_e[2 * s + t];
        int r = atomicAdd(&rankctr[e], 1);
        int p = basep[e] + r;
        arena_token[p] = s;
        pos_of[2 * s + t] = p;
    }
}

// ---------------- MFMA GEMM: 256x256, BK=64, 8 waves, 4-phase (r7 structure) ----
// MODE 0 = full (real path, r7-identical). MODE 1 = stage-only ablation (staging +
// vmcnt + barriers; no ds_read/MFMA/epilogue). MODE 2 = compute-only ablation
// (ds_read + MFMA + barriers on stale LDS; no staging; epilogue to scratch that the
// real MODE-0 dispatch fully overwrites afterwards).
template <int EPI, int MODE>
__global__ __launch_bounds__(512, 2) void moe_gemm(
    const unsigned short* __restrict__ Asrc, const unsigned short* __restrict__ Bw,
    const float* __restrict__ bias, unsigned short* __restrict__ hOut,
    float* __restrict__ fOut, const int* __restrict__ arena_token,
    const int* __restrict__ counts, const int* __restrict__ basep,
    int Kd, int Nd, int ny, int Klen) {
    int cpx = gridDim.x >> 3;
    int bid = blockIdx.x;
    int wid = (bid & 7) * cpx + (bid >> 3);
    int per = (Nd >> 8) * ny * EEXP;
    int ks  = wid / per;
    int rem = wid - ks * per;
    int my  = rem % ny;
    int ne  = rem / ny;
    int e   = ne % EEXP;
    int n   = ne / EEXP;

    int count = counts[e];
    int m0 = my * 256;
    if (m0 >= count) return;
    int base = basep[e];
    int n0 = n * 256;
    int kbase = ks * Klen;
    int tid = threadIdx.x, w = tid >> 6, l = tid & 63;

    float* fOutP = fOut + (size_t)ks * CAP * DDIM;

    __shared__ __align__(16) char smem[131072];

    // ---- stage source pointers (pre-swizzled k-chunk, lane-pure) ----
    int tr = tid >> 2;                               // 0..127
    int clog = ((tid & 3) ^ ((tid >> 3) & 3)) * 8;   // swizzled element offset
    const unsigned short *pA0, *pA1, *pB0, *pB1;
    {
        int r0 = m0 + tr, r1 = m0 + 128 + tr;
        int c0 = (r0 < count) ? r0 : (count - 1);
        int c1 = (r1 < count) ? r1 : (count - 1);
        if (EPI == 1) {
            pA0 = Asrc + (size_t)arena_token[base + c0] * Kd + kbase + clog;
            pA1 = Asrc + (size_t)arena_token[base + c1] * Kd + kbase + clog;
        } else {
            pA0 = Asrc + (size_t)(base + c0) * Kd + kbase + clog;
            pA1 = Asrc + (size_t)(base + c1) * Kd + kbase + clog;
        }
        pB0 = Bw + ((size_t)e * Nd + n0 + tr) * Kd + kbase + clog;
        pB1 = Bw + ((size_t)e * Nd + n0 + 128 + tr) * Kd + kbase + clog;
    }

#define SA(slot, kk, T) do { if (MODE != 2) {                          \
        int lb_ = (slot) * 65536 + (kk) * 16384 + w * 1024;            \
        size_t ko_ = (size_t)(T) * 64 + (size_t)(kk) * 32;             \
        gload16(pA0 + ko_, smem + lb_);                                \
        gload16(pA1 + ko_, smem + lb_ + 8192); } } while (0)
#define SB(slot, kk, T) do { if (MODE != 2) {                          \
        int lb_ = (slot) * 65536 + 32768 + (kk) * 16384 + w * 1024;    \
        size_t ko_ = (size_t)(T) * 64 + (size_t)(kk) * 32;             \
        gload16(pB0 + ko_, smem + lb_);                                \
        gload16(pB1 + ko_, smem + lb_ + 8192); } } while (0)

    // ---- fragment read addressing (PMC-verified conflict-free) ----
    int wm = w >> 2, wn = w & 3;
    int hi = l >> 4;
    int rdc = ((hi ^ ((l >> 1) & 3)) << 4);
    const char* Ar = smem + (size_t)(wm * 128 + (l & 15)) * 64 + rdc;
    const char* Br = smem + 32768 + (size_t)(wn * 64 + (l & 15)) * 64 + rdc;

    f32x4 acc[8][4];
#pragma unroll
    for (int i = 0; i < 8; ++i)
#pragma unroll
        for (int j = 0; j < 4; ++j) acc[i][j] = (f32x4){0.f, 0.f, 0.f, 0.f};

#define MM(bq, aq, mb) do { if (MODE != 1) {                                       \
        __builtin_amdgcn_s_setprio(1);                                             \
        _Pragma("unroll")                                                          \
        for (int mi = 0; mi < 4; ++mi)                                             \
            _Pragma("unroll")                                                      \
            for (int ni = 0; ni < 4; ++ni)                                         \
                acc[(mb) + mi][ni] = __builtin_amdgcn_mfma_f32_16x16x32_bf16(      \
                    aq[mi], bq[ni], acc[(mb) + mi][ni], 0, 0, 0);                  \
        __builtin_amdgcn_s_setprio(0); } } while (0)

#define OPENB()  do { __builtin_amdgcn_s_barrier();                                 \
        asm volatile("s_waitcnt lgkmcnt(0)" ::: "memory");                          \
        __builtin_amdgcn_sched_barrier(0); } while (0)
#define CLOSEB() do { __builtin_amdgcn_s_barrier();                                 \
        asm volatile("" ::: "memory"); } while (0)

    int nt = Klen >> 6;
    SA(0, 0, 0); SB(0, 0, 0); SA(0, 1, 0); SB(0, 1, 0);
    if (MODE != 2) { asm volatile("s_waitcnt vmcnt(4)" ::: "memory"); }
    __builtin_amdgcn_sched_barrier(0);
    CLOSEB();

    for (int t = 0; t < nt; ++t) {
        int cs = t & 1, ss = cs ^ 1;
        const char* Ab = Ar + cs * 65536;
        const char* Bb = Br + cs * 65536;
        bool pre = (t + 1 < nt);
        bf16x8 bq[4], aq[4];
        // ---- P0 ----
        if (MODE != 1) {
#pragma unroll
            for (int ni = 0; ni < 4; ++ni) bq[ni] = *(const bf16x8*)(Bb + ni * 1024);
#pragma unroll
            for (int mi = 0; mi < 4; ++mi) aq[mi] = *(const bf16x8*)(Ab + mi * 1024);
        }
        if (pre) SA(ss, 0, t + 1);
        OPENB();
        MM(bq, aq, 0);
        CLOSEB();
        // ---- P1 ----
        if (MODE != 1) {
#pragma unroll
            for (int mi = 0; mi < 4; ++mi) aq[mi] = *(const bf16x8*)(Ab + 4096 + mi * 1024);
        }
        if (pre) SB(ss, 0, t + 1);
        OPENB();
        MM(bq, aq, 4);
        if (MODE != 2) {
            if (pre) asm volatile("s_waitcnt vmcnt(4)" ::: "memory");
            else     asm volatile("s_waitcnt vmcnt(0)" ::: "memory");
        }
        __builtin_amdgcn_sched_barrier(0);
        CLOSEB();
        // ---- P2 ----
        if (MODE != 1) {
#pragma unroll
            for (int ni = 0; ni < 4; ++ni) bq[ni] = *(const bf16x8*)(Bb + 16384 + ni * 1024);
#pragma unroll
            for (int mi = 0; mi < 4; ++mi) aq[mi] = *(const bf16x8*)(Ab + 16384 + mi * 1024);
        }
        if (pre) SA(ss, 1, t + 1);
        OPENB();
        MM(bq, aq, 0);
        CLOSEB();
        // ---- P3 ----
        if (MODE != 1) {
#pragma unroll
            for (int mi = 0; mi < 4; ++mi) aq[mi] = *(const bf16x8*)(Ab + 20480 + mi * 1024);
        }
        if (pre) SB(ss, 1, t + 1);
        OPENB();
        MM(bq, aq, 4);
        if (MODE != 2) {
            if (pre) asm volatile("s_waitcnt vmcnt(4)" ::: "memory");
            else if (t + 1 < nt) asm volatile("s_waitcnt vmcnt(4)" ::: "memory");
            else asm volatile("s_waitcnt vmcnt(0)" ::: "memory");
        }
        __builtin_amdgcn_sched_barrier(0);
        CLOSEB();
    }
#undef SA
#undef SB
#undef MM
#undef OPENB
#undef CLOSEB

    if (MODE == 1) return;   // staging side effects already issued; no epilogue

    // Epilogue. C/D layout: col = lane&15, row = (lane>>4)*4 + reg  [m89 verified]
#pragma unroll
    for (int rf = 0; rf < 8; ++rf)
#pragma unroll
        for (int ni = 0; ni < 4; ++ni)
#pragma unroll
            for (int r = 0; r < 4; ++r) {
                int rl = wm * 128 + rf * 16 + hi * 4 + r;
                int gr = m0 + rl;
                if (gr < count) {
                    int col = n0 + wn * 64 + ni * 16 + (l & 15);
                    float v = acc[rf][ni][r];
                    if (EPI == 1) {
                        v += bias[e * Nd + col];
                        v = fmaxf(v, 0.f);
                        hOut[(size_t)(base + gr) * Nd + col] = f2bf(v);
                    } else {
                        fOutP[(size_t)(base + gr) * Nd + col] = v;
                    }
                }
            }
}

// Deterministic combine with 2 K-split partials.
__global__ void combine_k(const float* __restrict__ outP, const float* __restrict__ b2,
                          const int* __restrict__ topk_e, const float* __restrict__ topk_g,
                          const int* __restrict__ pos_of, float* __restrict__ y) {
    int idx = blockIdx.x * blockDim.x + threadIdx.x;
    int s = idx >> 8;
    int c = (idx & 255) * 4;
    int e0 = topk_e[2 * s], e1 = topk_e[2 * s + 1];
    float g0 = topk_g[2 * s], g1 = topk_g[2 * s + 1];
    int p0 = pos_of[2 * s], p1 = pos_of[2 * s + 1];
    const float* P1 = outP + (size_t)CAP * DDIM;
    float4 a0 = *(const float4*)(outP + (size_t)p0 * DDIM + c);
    float4 a1 = *(const float4*)(P1   + (size_t)p0 * DDIM + c);
    float4 b0v = *(const float4*)(outP + (size_t)p1 * DDIM + c);
    float4 b1v = *(const float4*)(P1   + (size_t)p1 * DDIM + c);
    float4 c0 = *(const float4*)(b2 + (size_t)e0 * DDIM + c);
    float4 c1 = *(const float4*)(b2 + (size_t)e1 * DDIM + c);
    float4 r;
    r.x = g0 * (a0.x + a1.x + c0.x) + g1 * (b0v.x + b1v.x + c1.x);
    r.y = g0 * (a0.y + a1.y + c0.y) + g1 * (b0v.y + b1v.y + c1.y);
    r.z = g0 * (a0.z + a1.z + c0.z) + g1 * (b0v.z + b1v.z + c1.z);
    r.w = g0 * (a0.w + a1.w + c0.w) + g1 * (b0v.w + b1v.w + c1.w);
    *(float4*)(y + (size_t)s * DDIM + c) = r;
}

extern "C" void kernel_launch(void* const* d_in, const int* in_sizes, int n_in,
                              void* d_out, int out_size, void* d_ws, size_t ws_size,
                              hipStream_t stream) {
    const float* x      = (const float*)d_in[0];
    const float* gate_w = (const float*)d_in[1];
    const float* w1     = (const float*)d_in[2];
    const float* b1     = (const float*)d_in[3];
    const float* w2     = (const float*)d_in[4];
    const float* b2     = (const float*)d_in[5];

    char* p = (char*)d_ws;
    unsigned short* w1b = (unsigned short*)p;   // 64 MB; reused as outP (2x32MB) after GEMM1
    float* outP         = (float*)p;            p += (size_t)EEXP * FDIM * DDIM * 2;
    unsigned short* w2b = (unsigned short*)p;   p += (size_t)EEXP * FDIM * DDIM * 2;
    unsigned short* xb  = (unsigned short*)p;   p += (size_t)S_TOK * DDIM * 2;
    unsigned short* hA  = (unsigned short*)p;   p += (size_t)CAP * FDIM * 2;
    int*   topk_e       = (int*)p;              p += S_TOK * 2 * 4;
    float* topk_g       = (float*)p;            p += S_TOK * 2 * 4;
    int*   pos_of       = (int*)p;              p += S_TOK * 2 * 4;
    int*   arena_token  = (int*)p;              p += CAP * 4;
    int*   counts       = (int*)p;              p += 64;
    int*   rankctr      = (int*)p;              p += 64;
    int*   basep        = (int*)p;              p += 64;
    (void)ws_size; (void)in_sizes; (void)n_in; (void)out_size;

    zero_k<<<1, 64, 0, stream>>>(counts, 48);

    cvt_bf16<<<2048, 256, 0, stream>>>(w1, w1b, EEXP * FDIM * DDIM / 4);
    cvt_bf16<<<2048, 256, 0, stream>>>(w2, w2b, EEXP * FDIM * DDIM / 4);

    router_k<<<S_TOK, 64, 0, stream>>>(x, gate_w, xb, topk_e, topk_g, counts);
    scan_k<<<1, 1, 0, stream>>>(counts, basep);
    scatter_k<<<S_TOK / 256, 256, 0, stream>>>(topk_e, rankctr, basep, arena_token, pos_of);

    // ---- DIAGNOSTIC ABLATIONS (GEMM1 shape; hA scratch fully overwritten below) ----
    moe_gemm<1, 1><<<dim3((FDIM / 256) * 16 * EEXP), 512, 0, stream>>>(   // V1: stage-only
        xb, w1b, b1, hA, nullptr, arena_token, counts, basep, DDIM, FDIM, 16, DDIM);
    moe_gemm<1, 2><<<dim3((FDIM / 256) * 16 * EEXP), 512, 0, stream>>>(   // V2: compute-only
        xb, w1b, b1, hA, nullptr, arena_token, counts, basep, DDIM, FDIM, 16, DDIM);

    // ---- REAL PATH (r7-identical) ----
    moe_gemm<1, 0><<<dim3((FDIM / 256) * 16 * EEXP), 512, 0, stream>>>(
        xb, w1b, b1, hA, nullptr, arena_token, counts, basep, DDIM, FDIM, 16, DDIM);
    moe_gemm<2, 0><<<dim3((DDIM / 256) * 16 * EEXP * 2), 512, 0, stream>>>(
        hA, w2b, nullptr, nullptr, outP, arena_token, counts, basep, FDIM, DDIM, 16, FDIM / 2);

    combine_k<<<S_TOK * DDIM / 4 / 256, 256, 0, stream>>>(
        outP, b2, topk_e, topk_g, pos_of, (float*)d_out);
}

// Round 11
// 475.859 us; speedup vs baseline: 1.3782x; 1.3782x over previous
//
#include <hip/hip_runtime.h>
#include <hip/hip_bf16.h>
#include <stdint.h>

// MoE FFN: B=2,T=2048,D=1024,F=4096,E=8,K=2. S=4096 tokens, 8192 assignments.
#define S_TOK 4096
#define DDIM  1024
#define FDIM  4096
#define EEXP  8
#define CAP   (S_TOK * 2)

typedef __bf16 bf16x8 __attribute__((ext_vector_type(8)));
typedef __bf16 bf16x4 __attribute__((ext_vector_type(4)));
typedef float  f32x4  __attribute__((ext_vector_type(4)));

__device__ __forceinline__ unsigned short f2bf(float f) {
    union { float f; unsigned u; } v; v.f = f;
    unsigned u = v.u;
    return (unsigned short)((u + 0x7FFFu + ((u >> 16) & 1u)) >> 16);  // RNE
}

// global -> LDS async copy, 16B/lane. Offset arg MUST stay 0 (r8 lesson).
__device__ __forceinline__ void gload16(const void* g, void* l) {
    auto gp = reinterpret_cast<const __attribute__((address_space(1))) uint32_t*>(
        reinterpret_cast<uintptr_t>(g));
    auto lp = reinterpret_cast<__attribute__((address_space(3))) uint32_t*>(
        static_cast<uint32_t>(reinterpret_cast<uintptr_t>(l)));
    __builtin_amdgcn_global_load_lds(gp, lp, 16, 0, 0);
}

// ---------------- small kernels ----------------

__global__ void zero_k(int* p, int n) {
    int i = threadIdx.x;
    if (i < n) p[i] = 0;
}

__global__ void cvt_bf16(const float* __restrict__ src, unsigned short* __restrict__ dst, int n4) {
    int stride = gridDim.x * blockDim.x;
    for (int i = blockIdx.x * blockDim.x + threadIdx.x; i < n4; i += stride) {
        float4 v = ((const float4*)src)[i];
        bf16x4 o = { (__bf16)v.x, (__bf16)v.y, (__bf16)v.z, (__bf16)v.w };
        ((bf16x4*)dst)[i] = o;
    }
}

// Router: one wave per token, fp32 (must match numpy top-2 selection). Fused x->bf16.
__global__ void router_k(const float* __restrict__ x, const float* __restrict__ gw,
                         unsigned short* __restrict__ xb,
                         int* __restrict__ topk_e, float* __restrict__ topk_g,
                         int* __restrict__ counts) {
    int s = blockIdx.x;
    int l = threadIdx.x;
    const float* xr = x + (size_t)s * DDIM;
    unsigned short* xbr = xb + (size_t)s * DDIM;
    float acc[EEXP];
#pragma unroll
    for (int e = 0; e < EEXP; ++e) acc[e] = 0.f;
    for (int i = 0; i < DDIM; i += 64) {
        float xv = xr[i + l];
        xbr[i + l] = f2bf(xv);
#pragma unroll
        for (int e = 0; e < EEXP; ++e) acc[e] = fmaf(xv, gw[e * DDIM + i + l], acc[e]);
    }
#pragma unroll
    for (int e = 0; e < EEXP; ++e)
        for (int off = 32; off > 0; off >>= 1) acc[e] += __shfl_down(acc[e], off, 64);
    if (l == 0) {
        float v0 = -1e30f, v1 = -1e30f; int i0 = 0, i1 = 0;
#pragma unroll
        for (int e = 0; e < EEXP; ++e) {
            float v = acc[e];
            if (v > v0)      { v1 = v0; i1 = i0; v0 = v; i0 = e; }
            else if (v > v1) { v1 = v;  i1 = e; }
        }
        float t = expf(v1 - v0);
        float d = 1.f + t;
        topk_e[2 * s] = i0; topk_e[2 * s + 1] = i1;
        topk_g[2 * s] = 1.f / d; topk_g[2 * s + 1] = t / d;
        atomicAdd(&counts[i0], 1);
        atomicAdd(&counts[i1], 1);
    }
}

__global__ void scan_k(const int* __restrict__ counts, int* __restrict__ basep) {
    if (threadIdx.x == 0) {
        int b = 0;
        for (int e = 0; e < EEXP; ++e) { basep[e] = b; b += counts[e]; }
    }
}

__global__ void scatter_k(const int* __restrict__ topk_e, int* __restrict__ rankctr,
                          const int* __restrict__ basep, int* __restrict__ arena_token,
                          int* __restrict__ pos_of) {
    int s = blockIdx.x * blockDim.x + threadIdx.x;
    if (s >= S_TOK) return;
#pragma unroll
    for (int t = 0; t < 2; ++t) {
        int e = topk_e[2 * s + t];
        int r = atomicAdd(&rankctr[e], 1);
        int p = basep[e] + r;
        arena_token[p] = s;
        pos_of[2 * s + t] = p;
    }
}

// ---------------- MFMA GEMM: BM=128 x BN=256, BK=32, 8 waves (2Mx4N), dbuf, 2 blocks/CU ----
// r10 ablation: staging = 100% of time; 256^2@1 block/CU ran 3.2 TB/s (lockstep duty-cycle),
// 128^2@2+ blocks/CU ran 5.9 TB/s (cross-block overlap, r1/r3). This config: 2 blocks/CU
// (LDS 48KB, VGPR forced <=128 via __launch_bounds__(512,4)) at 768MB staged volume.
// Simple r3-proven loop: STAGE(next buf); ds_read cur; MFMA; __syncthreads().
// Swizzle (64B rows, 4 chunks): chunk_phys = chunk_log ^ ((row>>1)&3); write side lane-pure
// (l&3)^((l>>3)&3); read side (l>>4)^((l>>1)&3). 16 lanes -> 8 banks x2 = conflict-free.
template <int EPI>
__global__ __launch_bounds__(512, 4) void moe_gemm(
    const unsigned short* __restrict__ Asrc, const unsigned short* __restrict__ Bw,
    const float* __restrict__ bias, unsigned short* __restrict__ hOut,
    float* __restrict__ fOut, const int* __restrict__ arena_token,
    const int* __restrict__ counts, const int* __restrict__ basep,
    int Kd, int Nd, int ny, int Klen) {
    int cpx = gridDim.x >> 3;
    int bid = blockIdx.x;
    int wid = (bid & 7) * cpx + (bid >> 3);
    int nx  = Nd >> 8;                 // BN = 256
    int per = nx * ny * EEXP;
    int ks  = wid / per;
    int rem = wid - ks * per;
    int my  = rem % ny;
    int ne  = rem / ny;
    int e   = ne % EEXP;
    int n   = ne / EEXP;

    int count = counts[e];
    int m0 = my * 128;
    if (m0 >= count) return;
    int base = basep[e];
    int n0 = n * 256;
    int kbase = ks * Klen;
    int tid = threadIdx.x, w = tid >> 6, l = tid & 63;

    float* fOutP = fOut + (size_t)ks * CAP * DDIM;

    // buf: A 8KB @0 (rows 0..127 x 64B), B 16KB @8192 (rows 0..255 x 64B). BUF=24576.
    __shared__ __align__(16) char smem[2 * 24576];

    // ---- stage source pointers (pre-swizzled k-chunk, lane-pure); bumped +32 elem/K-tile ----
    int clog = ((l & 3) ^ ((l >> 3) & 3)) * 8;       // swizzled element offset in K-tile
    const unsigned short *pA0, *pB0, *pB1;
    {
        int ra = m0 + w * 16 + (l >> 2);             // A row (one per wave: 8x16=128)
        int ca = (ra < count) ? ra : (count - 1);
        if (EPI == 1) {
            pA0 = Asrc + (size_t)arena_token[base + ca] * Kd + kbase + clog;
        } else {
            pA0 = Asrc + (size_t)(base + ca) * Kd + kbase + clog;
        }
        int rb = w * 32 + (l >> 2);                  // B rows (two per wave: 8x32=256)
        pB0 = Bw + ((size_t)e * Nd + n0 + rb) * Kd + kbase + clog;
        pB1 = Bw + ((size_t)e * Nd + n0 + rb + 16) * Kd + kbase + clog;
    }

#define STG(sb) do {                                                   \
        char* d_ = smem + (sb) * 24576;                                \
        gload16(pA0, d_ + w * 1024);                                   \
        gload16(pB0, d_ + 8192 + w * 2048);                            \
        gload16(pB1, d_ + 8192 + w * 2048 + 1024);                     \
    } while (0)

    // ---- fragment read addressing ----
    int wm = w >> 2, wn = w & 3;                 // 2(M) x 4(N) waves, wave tile 64x64
    int hi = l >> 4;
    int rdc = ((hi ^ ((l >> 1) & 3)) << 4);      // swizzled 16B chunk (lane-pure)
    const char* Ar = smem + (size_t)(wm * 64 + (l & 15)) * 64 + rdc;
    const char* Br = smem + 8192 + (size_t)(wn * 64 + (l & 15)) * 64 + rdc;

    f32x4 acc[4][4];
#pragma unroll
    for (int i = 0; i < 4; ++i)
#pragma unroll
        for (int j = 0; j < 4; ++j) acc[i][j] = (f32x4){0.f, 0.f, 0.f, 0.f};

    int nt = Klen >> 5;
    STG(0);
    __syncthreads();

    for (int t = 0; t < nt; ++t) {
        int cs = t & 1;
        if (t + 1 < nt) {
            pA0 += 32; pB0 += 32; pB1 += 32;
            STG(cs ^ 1);
        }
        const char* Ab = Ar + cs * 24576;
        const char* Bb = Br + cs * 24576;
        bf16x8 bq[4];
#pragma unroll
        for (int ni = 0; ni < 4; ++ni) bq[ni] = *(const bf16x8*)(Bb + ni * 1024);
#pragma unroll
        for (int mi = 0; mi < 4; ++mi) {
            bf16x8 a = *(const bf16x8*)(Ab + mi * 1024);
#pragma unroll
            for (int ni = 0; ni < 4; ++ni)
                acc[mi][ni] = __builtin_amdgcn_mfma_f32_16x16x32_bf16(a, bq[ni], acc[mi][ni], 0, 0, 0);
        }
        __syncthreads();   // drains vmcnt+lgkm: buf[cs] reads done before next overwrite
    }
#undef STG

    // Epilogue. C/D layout: col = lane&15, row = (lane>>4)*4 + reg  [m89 verified]
#pragma unroll
    for (int mi = 0; mi < 4; ++mi)
#pragma unroll
        for (int ni = 0; ni < 4; ++ni)
#pragma unroll
            for (int r = 0; r < 4; ++r) {
                int rl = wm * 64 + mi * 16 + hi * 4 + r;
                int gr = m0 + rl;
                if (gr < count) {
                    int col = n0 + wn * 64 + ni * 16 + (l & 15);
                    float v = acc[mi][ni][r];
                    if (EPI == 1) {
                        v += bias[e * Nd + col];
                        v = fmaxf(v, 0.f);
                        hOut[(size_t)(base + gr) * Nd + col] = f2bf(v);
                    } else {
                        fOutP[(size_t)(base + gr) * Nd + col] = v;
                    }
                }
            }
}

// Deterministic combine with 2 K-split partials.
__global__ void combine_k(const float* __restrict__ outP, const float* __restrict__ b2,
                          const int* __restrict__ topk_e, const float* __restrict__ topk_g,
                          const int* __restrict__ pos_of, float* __restrict__ y) {
    int idx = blockIdx.x * blockDim.x + threadIdx.x;
    int s = idx >> 8;
    int c = (idx & 255) * 4;
    int e0 = topk_e[2 * s], e1 = topk_e[2 * s + 1];
    float g0 = topk_g[2 * s], g1 = topk_g[2 * s + 1];
    int p0 = pos_of[2 * s], p1 = pos_of[2 * s + 1];
    const float* P1 = outP + (size_t)CAP * DDIM;
    float4 a0 = *(const float4*)(outP + (size_t)p0 * DDIM + c);
    float4 a1 = *(const float4*)(P1   + (size_t)p0 * DDIM + c);
    float4 b0v = *(const float4*)(outP + (size_t)p1 * DDIM + c);
    float4 b1v = *(const float4*)(P1   + (size_t)p1 * DDIM + c);
    float4 c0 = *(const float4*)(b2 + (size_t)e0 * DDIM + c);
    float4 c1 = *(const float4*)(b2 + (size_t)e1 * DDIM + c);
    float4 r;
    r.x = g0 * (a0.x + a1.x + c0.x) + g1 * (b0v.x + b1v.x + c1.x);
    r.y = g0 * (a0.y + a1.y + c0.y) + g1 * (b0v.y + b1v.y + c1.y);
    r.z = g0 * (a0.z + a1.z + c0.z) + g1 * (b0v.z + b1v.z + c1.z);
    r.w = g0 * (a0.w + a1.w + c0.w) + g1 * (b0v.w + b1v.w + c1.w);
    *(float4*)(y + (size_t)s * DDIM + c) = r;
}

extern "C" void kernel_launch(void* const* d_in, const int* in_sizes, int n_in,
                              void* d_out, int out_size, void* d_ws, size_t ws_size,
                              hipStream_t stream) {
    const float* x      = (const float*)d_in[0];
    const float* gate_w = (const float*)d_in[1];
    const float* w1     = (const float*)d_in[2];
    const float* b1     = (const float*)d_in[3];
    const float* w2     = (const float*)d_in[4];
    const float* b2     = (const float*)d_in[5];

    char* p = (char*)d_ws;
    unsigned short* w1b = (unsigned short*)p;   // 64 MB; reused as outP (2x32MB) after GEMM1
    float* outP         = (float*)p;            p += (size_t)EEXP * FDIM * DDIM * 2;
    unsigned short* w2b = (unsigned short*)p;   p += (size_t)EEXP * FDIM * DDIM * 2;
    unsigned short* xb  = (unsigned short*)p;   p += (size_t)S_TOK * DDIM * 2;
    unsigned short* hA  = (unsigned short*)p;   p += (size_t)CAP * FDIM * 2;
    int*   topk_e       = (int*)p;              p += S_TOK * 2 * 4;
    float* topk_g       = (float*)p;            p += S_TOK * 2 * 4;
    int*   pos_of       = (int*)p;              p += S_TOK * 2 * 4;
    int*   arena_token  = (int*)p;              p += CAP * 4;
    int*   counts       = (int*)p;              p += 64;
    int*   rankctr      = (int*)p;              p += 64;
    int*   basep        = (int*)p;              p += 64;
    (void)ws_size; (void)in_sizes; (void)n_in; (void)out_size;

    zero_k<<<1, 64, 0, stream>>>(counts, 48);

    cvt_bf16<<<4096, 256, 0, stream>>>(w1, w1b, EEXP * FDIM * DDIM / 4);
    cvt_bf16<<<4096, 256, 0, stream>>>(w2, w2b, EEXP * FDIM * DDIM / 4);

    router_k<<<S_TOK, 64, 0, stream>>>(x, gate_w, xb, topk_e, topk_g, counts);
    scan_k<<<1, 1, 0, stream>>>(counts, basep);
    scatter_k<<<S_TOK / 256, 256, 0, stream>>>(topk_e, rankctr, basep, arena_token, pos_of);

    // GEMM1: BM=128 tiles over gathered rows; grid = nx(16) * ny(32) * E(8) = 4096.
    moe_gemm<1><<<dim3((FDIM / 256) * 32 * EEXP), 512, 0, stream>>>(
        xb, w1b, b1, hA, nullptr, arena_token, counts, basep, DDIM, FDIM, 32, DDIM);
    // GEMM2: K=4096 split 2; grid = nx(4) * ny(32) * E(8) * KS(2) = 2048 (512 active = 2/CU).
    moe_gemm<2><<<dim3((DDIM / 256) * 32 * EEXP * 2), 512, 0, stream>>>(
        hA, w2b, nullptr, nullptr, outP, arena_token, counts, basep, FDIM, DDIM, 32, FDIM / 2);

    combine_k<<<S_TOK * DDIM / 4 / 256, 256, 0, stream>>>(
        outP, b2, topk_e, topk_g, pos_of, (float*)d_out);
}

// Round 13
// 453.492 us; speedup vs baseline: 1.4461x; 1.0493x over previous
//
#include <hip/hip_runtime.h>
#include <hip/hip_bf16.h>
#include <stdint.h>

// MoE FFN: B=2,T=2048,D=1024,F=4096,E=8,K=2. S=4096 tokens, 8192 assignments.
#define S_TOK 4096
#define DDIM  1024
#define FDIM  4096
#define EEXP  8
#define CAP   (S_TOK * 2)
#define BUF   24576

typedef __bf16 bf16x8 __attribute__((ext_vector_type(8)));
typedef __bf16 bf16x4 __attribute__((ext_vector_type(4)));
typedef float  f32x4  __attribute__((ext_vector_type(4)));

__device__ __forceinline__ unsigned short f2bf(float f) {
    union { float f; unsigned u; } v; v.f = f;
    unsigned u = v.u;
    return (unsigned short)((u + 0x7FFFu + ((u >> 16) & 1u)) >> 16);  // RNE
}

// global -> LDS async copy, 16B/lane. Offset arg MUST stay 0 (r8 lesson).
__device__ __forceinline__ void gload16(const void* g, void* l) {
    auto gp = reinterpret_cast<const __attribute__((address_space(1))) uint32_t*>(
        reinterpret_cast<uintptr_t>(g));
    auto lp = reinterpret_cast<__attribute__((address_space(3))) uint32_t*>(
        static_cast<uint32_t>(reinterpret_cast<uintptr_t>(l)));
    __builtin_amdgcn_global_load_lds(gp, lp, 16, 0, 0);
}

// ---------------- small kernels ----------------

__global__ void zero_k(int* p, int n) {
    int i = threadIdx.x;
    if (i < n) p[i] = 0;
}

__global__ void cvt_bf16(const float* __restrict__ src, unsigned short* __restrict__ dst, int n4) {
    int stride = gridDim.x * blockDim.x;
    for (int i = blockIdx.x * blockDim.x + threadIdx.x; i < n4; i += stride) {
        float4 v = ((const float4*)src)[i];
        bf16x4 o = { (__bf16)v.x, (__bf16)v.y, (__bf16)v.z, (__bf16)v.w };
        ((bf16x4*)dst)[i] = o;
    }
}

// Router: one wave per token, fp32 (must match numpy top-2 selection). Fused x->bf16.
__global__ void router_k(const float* __restrict__ x, const float* __restrict__ gw,
                         unsigned short* __restrict__ xb,
                         int* __restrict__ topk_e, float* __restrict__ topk_g,
                         int* __restrict__ counts) {
    int s = blockIdx.x;
    int l = threadIdx.x;
    const float* xr = x + (size_t)s * DDIM;
    unsigned short* xbr = xb + (size_t)s * DDIM;
    float acc[EEXP];
#pragma unroll
    for (int e = 0; e < EEXP; ++e) acc[e] = 0.f;
    for (int i = 0; i < DDIM; i += 64) {
        float xv = xr[i + l];
        xbr[i + l] = f2bf(xv);
#pragma unroll
        for (int e = 0; e < EEXP; ++e) acc[e] = fmaf(xv, gw[e * DDIM + i + l], acc[e]);
    }
#pragma unroll
    for (int e = 0; e < EEXP; ++e)
        for (int off = 32; off > 0; off >>= 1) acc[e] += __shfl_down(acc[e], off, 64);
    if (l == 0) {
        float v0 = -1e30f, v1 = -1e30f; int i0 = 0, i1 = 0;
#pragma unroll
        for (int e = 0; e < EEXP; ++e) {
            float v = acc[e];
            if (v > v0)      { v1 = v0; i1 = i0; v0 = v; i0 = e; }
            else if (v > v1) { v1 = v;  i1 = e; }
        }
        float t = expf(v1 - v0);
        float d = 1.f + t;
        topk_e[2 * s] = i0; topk_e[2 * s + 1] = i1;
        topk_g[2 * s] = 1.f / d; topk_g[2 * s + 1] = t / d;
        atomicAdd(&counts[i0], 1);
        atomicAdd(&counts[i1], 1);
    }
}

__global__ void scan_k(const int* __restrict__ counts, int* __restrict__ basep) {
    if (threadIdx.x == 0) {
        int b = 0;
        for (int e = 0; e < EEXP; ++e) { basep[e] = b; b += counts[e]; }
    }
}

__global__ void scatter_k(const int* __restrict__ topk_e, int* __restrict__ rankctr,
                          const int* __restrict__ basep, int* __restrict__ arena_token,
                          int* __restrict__ pos_of) {
    int s = blockIdx.x * blockDim.x + threadIdx.x;
    if (s >= S_TOK) return;
#pragma unroll
    for (int t = 0; t < 2; ++t) {
        int e = topk_e[2 * s + t];
        int r = atomicAdd(&rankctr[e], 1);
        int p = basep[e] + r;
        arena_token[p] = s;
        pos_of[2 * s + t] = p;
    }
}

// ---------------- MFMA GEMM: BM=128 x BN=256, BK=32, 8 waves, TRIPLE-buffer lookahead-2 ----
// r12 bug (absmax 2.2): prologue staged 3 tiles AND loop staged t+3 into the slot being
// read. With 3 slots max safe lookahead is 2. Corrected pipeline:
//   prologue: STG tile0->slot0, tile1->slot1 (6 outstanding); vmcnt(3) -> tile0 landed.
//   iter t:   [t+2<nt] STG tile t+2 -> slot (t+2)%3  (slot == (t-1)%3, consumed before
//             iter t-1's closing barrier -> WAR-safe);
//             ds_read slot t%3; MFMA;
//             close vmcnt(3) (tile t+1 landed, tile t+2 floats) / vmcnt(0) at tail; barrier.
// 2 blocks/CU (72KB LDS, ~52 VGPR). Staging never drains to 0 in steady state.
template <int EPI>
__global__ __launch_bounds__(512, 4) void moe_gemm(
    const unsigned short* __restrict__ Asrc, const unsigned short* __restrict__ Bw,
    const float* __restrict__ bias, unsigned short* __restrict__ hOut,
    float* __restrict__ fOut, const int* __restrict__ arena_token,
    const int* __restrict__ counts, const int* __restrict__ basep,
    int Kd, int Nd, int ny, int Klen) {
    int cpx = gridDim.x >> 3;
    int bid = blockIdx.x;
    int wid = (bid & 7) * cpx + (bid >> 3);
    int nx  = Nd >> 8;                 // BN = 256
    int per = nx * ny * EEXP;
    int ks  = wid / per;
    int rem = wid - ks * per;
    int my  = rem % ny;
    int ne  = rem / ny;
    int e   = ne % EEXP;
    int n   = ne / EEXP;

    int count = counts[e];
    int m0 = my * 128;
    if (m0 >= count) return;
    int base = basep[e];
    int n0 = n * 256;
    int kbase = ks * Klen;
    int tid = threadIdx.x, w = tid >> 6, l = tid & 63;

    float* fOutP = fOut + (size_t)ks * CAP * DDIM;

    // slot: A 8KB @0 (128 rows x 64B), B 16KB @8192 (256 rows x 64B).
    __shared__ __align__(16) char smem[3 * BUF];

    // ---- stage source pointers (pre-swizzled k-chunk, lane-pure); bumped +32 elem/stage ----
    int clog = ((l & 3) ^ ((l >> 3) & 3)) * 8;       // swizzled element offset in K-tile
    const unsigned short *pA0, *pB0, *pB1;
    {
        int ra = m0 + w * 16 + (l >> 2);             // A row (one per wave: 8x16=128)
        int ca = (ra < count) ? ra : (count - 1);
        if (EPI == 1) {
            pA0 = Asrc + (size_t)arena_token[base + ca] * Kd + kbase + clog;
        } else {
            pA0 = Asrc + (size_t)(base + ca) * Kd + kbase + clog;
        }
        int rb = w * 32 + (l >> 2);                  // B rows (two per wave: 8x32=256)
        pB0 = Bw + ((size_t)e * Nd + n0 + rb) * Kd + kbase + clog;
        pB1 = Bw + ((size_t)e * Nd + n0 + rb + 16) * Kd + kbase + clog;
    }

#define STG(sb) do {                                                   \
        char* d_ = smem + (sb) * BUF;                                  \
        gload16(pA0, d_ + w * 1024);                                   \
        gload16(pB0, d_ + 8192 + w * 2048);                            \
        gload16(pB1, d_ + 8192 + w * 2048 + 1024);                     \
        pA0 += 32; pB0 += 32; pB1 += 32;                               \
    } while (0)

    // ---- fragment read addressing (conflict-free swizzle, PMC-verified) ----
    int wm = w >> 2, wn = w & 3;                 // 2(M) x 4(N) waves, wave tile 64x64
    int hi = l >> 4;
    int rdc = ((hi ^ ((l >> 1) & 3)) << 4);      // swizzled 16B chunk (lane-pure)
    const char* Ar = smem + (size_t)(wm * 64 + (l & 15)) * 64 + rdc;
    const char* Br = smem + 8192 + (size_t)(wn * 64 + (l & 15)) * 64 + rdc;

    f32x4 acc[4][4];
#pragma unroll
    for (int i = 0; i < 4; ++i)
#pragma unroll
        for (int j = 0; j < 4; ++j) acc[i][j] = (f32x4){0.f, 0.f, 0.f, 0.f};

    int nt = Klen >> 5;                          // 32 or 64, always >= 3
    // prologue: lookahead-2 only (r12 fix) — tiles 0,1 into slots 0,1.
    STG(0); STG(1);
    asm volatile("s_waitcnt vmcnt(3)" ::: "memory");   // tile0 landed; tile1 in flight
    __builtin_amdgcn_sched_barrier(0);
    __builtin_amdgcn_s_barrier();
    asm volatile("" ::: "memory");

    int cs = 0, ss = 2;   // consume slot t%3; stage tile t+2 into slot (t+2)%3
    for (int t = 0; t < nt; ++t) {
        bool pre = (t + 2 < nt);
        if (pre) STG(ss);
        const char* Ab = Ar + cs * BUF;
        const char* Bb = Br + cs * BUF;
        bf16x8 bq[4];
#pragma unroll
        for (int ni = 0; ni < 4; ++ni) bq[ni] = *(const bf16x8*)(Bb + ni * 1024);
#pragma unroll
        for (int mi = 0; mi < 4; ++mi) {
            bf16x8 a = *(const bf16x8*)(Ab + mi * 1024);
#pragma unroll
            for (int ni = 0; ni < 4; ++ni)
                acc[mi][ni] = __builtin_amdgcn_mfma_f32_16x16x32_bf16(a, bq[ni], acc[mi][ni], 0, 0, 0);
        }
        if (pre) asm volatile("s_waitcnt vmcnt(3)" ::: "memory");  // t+1 landed; t+2 floats
        else     asm volatile("s_waitcnt vmcnt(0)" ::: "memory");  // tail drain
        __builtin_amdgcn_sched_barrier(0);
        __builtin_amdgcn_s_barrier();
        asm volatile("" ::: "memory");
        cs = (cs == 2) ? 0 : cs + 1;
        ss = (ss == 2) ? 0 : ss + 1;
    }
#undef STG

    // Epilogue. C/D layout: col = lane&15, row = (lane>>4)*4 + reg  [m89 verified]
#pragma unroll
    for (int mi = 0; mi < 4; ++mi)
#pragma unroll
        for (int ni = 0; ni < 4; ++ni)
#pragma unroll
            for (int r = 0; r < 4; ++r) {
                int rl = wm * 64 + mi * 16 + hi * 4 + r;
                int gr = m0 + rl;
                if (gr < count) {
                    int col = n0 + wn * 64 + ni * 16 + (l & 15);
                    float v = acc[mi][ni][r];
                    if (EPI == 1) {
                        v += bias[e * Nd + col];
                        v = fmaxf(v, 0.f);
                        hOut[(size_t)(base + gr) * Nd + col] = f2bf(v);
                    } else {
                        fOutP[(size_t)(base + gr) * Nd + col] = v;
                    }
                }
            }
}

// Deterministic combine with 2 K-split partials.
__global__ void combine_k(const float* __restrict__ outP, const float* __restrict__ b2,
                          const int* __restrict__ topk_e, const float* __restrict__ topk_g,
                          const int* __restrict__ pos_of, float* __restrict__ y) {
    int idx = blockIdx.x * blockDim.x + threadIdx.x;
    int s = idx >> 8;
    int c = (idx & 255) * 4;
    int e0 = topk_e[2 * s], e1 = topk_e[2 * s + 1];
    float g0 = topk_g[2 * s], g1 = topk_g[2 * s + 1];
    int p0 = pos_of[2 * s], p1 = pos_of[2 * s + 1];
    const float* P1 = outP + (size_t)CAP * DDIM;
    float4 a0 = *(const float4*)(outP + (size_t)p0 * DDIM + c);
    float4 a1 = *(const float4*)(P1   + (size_t)p0 * DDIM + c);
    float4 b0v = *(const float4*)(outP + (size_t)p1 * DDIM + c);
    float4 b1v = *(const float4*)(P1   + (size_t)p1 * DDIM + c);
    float4 c0 = *(const float4*)(b2 + (size_t)e0 * DDIM + c);
    float4 c1 = *(const float4*)(b2 + (size_t)e1 * DDIM + c);
    float4 r;
    r.x = g0 * (a0.x + a1.x + c0.x) + g1 * (b0v.x + b1v.x + c1.x);
    r.y = g0 * (a0.y + a1.y + c0.y) + g1 * (b0v.y + b1v.y + c1.y);
    r.z = g0 * (a0.z + a1.z + c0.z) + g1 * (b0v.z + b1v.z + c1.z);
    r.w = g0 * (a0.w + a1.w + c0.w) + g1 * (b0v.w + b1v.w + c1.w);
    *(float4*)(y + (size_t)s * DDIM + c) = r;
}

extern "C" void kernel_launch(void* const* d_in, const int* in_sizes, int n_in,
                              void* d_out, int out_size, void* d_ws, size_t ws_size,
                              hipStream_t stream) {
    const float* x      = (const float*)d_in[0];
    const float* gate_w = (const float*)d_in[1];
    const float* w1     = (const float*)d_in[2];
    const float* b1     = (const float*)d_in[3];
    const float* w2     = (const float*)d_in[4];
    const float* b2     = (const float*)d_in[5];

    char* p = (char*)d_ws;
    unsigned short* w1b = (unsigned short*)p;   // 64 MB; reused as outP (2x32MB) after GEMM1
    float* outP         = (float*)p;            p += (size_t)EEXP * FDIM * DDIM * 2;
    unsigned short* w2b = (unsigned short*)p;   p += (size_t)EEXP * FDIM * DDIM * 2;
    unsigned short* xb  = (unsigned short*)p;   p += (size_t)S_TOK * DDIM * 2;
    unsigned short* hA  = (unsigned short*)p;   p += (size_t)CAP * FDIM * 2;
    int*   topk_e       = (int*)p;              p += S_TOK * 2 * 4;
    float* topk_g       = (float*)p;            p += S_TOK * 2 * 4;
    int*   pos_of       = (int*)p;              p += S_TOK * 2 * 4;
    int*   arena_token  = (int*)p;              p += CAP * 4;
    int*   counts       = (int*)p;              p += 64;
    int*   rankctr      = (int*)p;              p += 64;
    int*   basep        = (int*)p;              p += 64;
    (void)ws_size; (void)in_sizes; (void)n_in; (void)out_size;

    zero_k<<<1, 64, 0, stream>>>(counts, 48);

    cvt_bf16<<<4096, 256, 0, stream>>>(w1, w1b, EEXP * FDIM * DDIM / 4);
    cvt_bf16<<<4096, 256, 0, stream>>>(w2, w2b, EEXP * FDIM * DDIM / 4);

    router_k<<<S_TOK, 64, 0, stream>>>(x, gate_w, xb, topk_e, topk_g, counts);
    scan_k<<<1, 1, 0, stream>>>(counts, basep);
    scatter_k<<<S_TOK / 256, 256, 0, stream>>>(topk_e, rankctr, basep, arena_token, pos_of);

    // GEMM1: grid = nx(16) * ny(32) * E(8) = 4096 (active ~1024 = 2+/CU).
    moe_gemm<1><<<dim3((FDIM / 256) * 32 * EEXP), 512, 0, stream>>>(
        xb, w1b, b1, hA, nullptr, arena_token, counts, basep, DDIM, FDIM, 32, DDIM);
    // GEMM2: K=4096 split 2; grid = nx(4) * ny(32) * E(8) * KS(2) = 2048 (active ~512 = 2/CU).
    moe_gemm<2><<<dim3((DDIM / 256) * 32 * EEXP * 2), 512, 0, stream>>>(
        hA, w2b, nullptr, nullptr, outP, arena_token, counts, basep, FDIM, DDIM, 32, FDIM / 2);

    combine_k<<<S_TOK * DDIM / 4 / 256, 256, 0, stream>>>(
        outP, b2, topk_e, topk_g, pos_of, (float*)d_out);
}